// Round 11
// baseline (1575.316 us; speedup 1.0000x reference)
//
#include <hip/hip_runtime.h>

#define TPB 1024
#define BM 64
#define AS 128   // activation row stride in floats (swizzled)

// ===========================================================================
// CSR build: count -> block scan -> fixup -> scatter. Rebuilt every call.
// ===========================================================================
__global__ void count_kernel(const int* __restrict__ ei, int* __restrict__ cnt, int E)
{
    int e = blockIdx.x * blockDim.x + threadIdx.x;
    if (e >= E) return;
    atomicAdd(cnt + ei[E + e], 1);
}

__global__ void scan_blocks(const int* __restrict__ cnt, int* __restrict__ rs,
                            int* __restrict__ part, int N)
{
    __shared__ int sums[256];
    int t = threadIdx.x;
    int base = blockIdx.x * 2048 + t * 8;
    int v[8], s = 0;
#pragma unroll
    for (int i = 0; i < 8; i++) { int idx = base + i; v[i] = (idx < N) ? cnt[idx] : 0; s += v[i]; }
    sums[t] = s;
    __syncthreads();
    for (int off = 1; off < 256; off <<= 1) {
        int x = (t >= off) ? sums[t - off] : 0;
        __syncthreads();
        if (t >= off) sums[t] += x;
        __syncthreads();
    }
    int run = (t == 0) ? 0 : sums[t - 1];
#pragma unroll
    for (int i = 0; i < 8; i++) { int idx = base + i; if (idx < N) rs[idx] = run; run += v[i]; }
    if (t == 255) part[blockIdx.x] = sums[255];
}

__global__ void scan_part(int* __restrict__ part, int nb)
{
    __shared__ int sums[256];
    int t = threadIdx.x;
    int base = t * 8;
    int v[8], s = 0;
#pragma unroll
    for (int i = 0; i < 8; i++) { int idx = base + i; v[i] = (idx < nb) ? part[idx] : 0; s += v[i]; }
    sums[t] = s;
    __syncthreads();
    for (int off = 1; off < 256; off <<= 1) {
        int x = (t >= off) ? sums[t - off] : 0;
        __syncthreads();
        if (t >= off) sums[t] += x;
        __syncthreads();
    }
    int run = (t == 0) ? 0 : sums[t - 1];
#pragma unroll
    for (int i = 0; i < 8; i++) { int idx = base + i; if (idx < nb) part[idx] = run; run += v[i]; }
}

__global__ void scan_fixup(int* __restrict__ rs, int* __restrict__ cursor,
                           const int* __restrict__ part, int N, int E)
{
    int i = blockIdx.x * blockDim.x + threadIdx.x;
    if (i < N) { int v = rs[i] + part[i >> 11]; rs[i] = v; cursor[i] = v; }
    if (i == 0) rs[N] = E;
}

__global__ void scatter_kernel(const int* __restrict__ ei, int* __restrict__ cursor,
                               int* __restrict__ col, int E)
{
    int e = blockIdx.x * blockDim.x + threadIdx.x;
    if (e >= E) return;
    int d = ei[E + e];
    int p = atomicAdd(cursor + d, 1);
    col[p] = ei[e];
}

// ===========================================================================
// act LDS swizzle: float4-slot XOR'd with (row&7); row-stride (lane=row)
// accesses spread across all banks.
// ===========================================================================
__device__ __forceinline__ int swz(int r, int col)
{
    return r * AS + ((((col >> 2) ^ (r & 7)) << 2) | (col & 3));
}

// ===========================================================================
// Scalar-weight GEMM layer: 16 waves; wave = 64 rows (lane=row) x CW=C/16
// columns. W[k][c] wave-uniform -> s_load through K$ (SGPR operand of
// v_fma_f32, zero VGPR cost). Per-thread state: acc[CW<=8] + float4 + addr
// ~= 24-28 VGPRs -> fits the 32-reg granule (8 waves/SIMD) without spill.
//   act[r][0:C] = f(sum_k act[r][k]*W[k][c] + scale(r)*bias[c])  in place
// ===========================================================================
template<int C, bool RELU>
__device__ __forceinline__ void scalar_gemm(
    float* __restrict__ act,
    const float* __restrict__ Wg, const float* __restrict__ bias_g,
    const float* __restrict__ ldeg,            // non-null: scale = ldeg[r]
    int K_real, int K_pad,                     // K_pad multiple of 4
    float* __restrict__ state_g, long base, int n)
{
    constexpr int CW = C / 16;                 // columns per wave (8 or 4)
    const int tid  = threadIdx.x;
    const int wid  = __builtin_amdgcn_readfirstlane(tid >> 6);  // uniform
    const int lane = tid & 63;
    const int r    = lane;                     // lane = row
    const int c0   = wid * CW;                 // wave-uniform column base

    float acc[CW];
#pragma unroll
    for (int j = 0; j < CW; j++) acc[j] = 0.0f;

    for (int k4 = 0; k4 < K_pad; k4 += 4) {
        float4 a = *(const float4*)(act + r * AS + (((k4 >> 2) ^ (r & 7)) << 2));
#pragma unroll
        for (int kk = 0; kk < 4; kk++) {
            int gk = k4 + kk;
            int wrow = (gk < K_real) ? gk : 0;       // clamp (act pad col = 0)
            float av = (&a.x)[kk];
            const float* wr = Wg + (long)wrow * C + c0;   // uniform -> s_load
#pragma unroll
            for (int j4 = 0; j4 < CW / 4; j4++) {
                float4 wv = *(const float4*)(wr + j4 * 4);
                acc[j4 * 4 + 0] = fmaf(av, wv.x, acc[j4 * 4 + 0]);
                acc[j4 * 4 + 1] = fmaf(av, wv.y, acc[j4 * 4 + 1]);
                acc[j4 * 4 + 2] = fmaf(av, wv.z, acc[j4 * 4 + 2]);
                acc[j4 * 4 + 3] = fmaf(av, wv.w, acc[j4 * 4 + 3]);
            }
        }
    }
    float scale = (ldeg != nullptr) ? ldeg[r] : 1.0f;
    __syncthreads();       // all waves' act reads complete
#pragma unroll
    for (int j4 = 0; j4 < CW / 4; j4++) {
        int cc = c0 + j4 * 4;
        float4 bv = *(const float4*)(bias_g + cc);        // uniform -> s_load
        float4 o;
        o.x = acc[j4 * 4 + 0] + scale * bv.x;
        o.y = acc[j4 * 4 + 1] + scale * bv.y;
        o.z = acc[j4 * 4 + 2] + scale * bv.z;
        o.w = acc[j4 * 4 + 3] + scale * bv.w;
        if (RELU) {
            o.x = fmaxf(o.x, 0.0f); o.y = fmaxf(o.y, 0.0f);
            o.z = fmaxf(o.z, 0.0f); o.w = fmaxf(o.w, 0.0f);
        }
        *(float4*)(act + r * AS + (((cc >> 2) ^ (r & 7)) << 2)) = o;
        if (state_g != nullptr && base + r < n)
            *(float4*)(state_g + (base + r) * 64 + cc) = o;
    }
    __syncthreads();       // new act visible
}

// ===========================================================================
// Fused per-64-node-tile: CSR gather -> layer0 -> update MLP -> predictor.
// TPB=1024 (16 waves). LDS = 32KB act -> 2 blocks/CU = 32 waves/CU, needs
// VGPR <= 32 (HW allocates in pow2 granules: 33..64 all cost 64 -> 4
// waves/SIMD, measured r9/r10). launch_bounds(1024,8) -> empirical cap 32.
// ===========================================================================
template<int K0>
__global__ __launch_bounds__(TPB, 8)
void fused_kernel(const int* __restrict__ rs, const int* __restrict__ col,
                  const float* __restrict__ srcdat, int nvar,
                  const float* __restrict__ xg,
                  const float* __restrict__ W0, const float* __restrict__ b0,
                  const float* __restrict__ uW1, const float* __restrict__ ub1,
                  const float* __restrict__ uW2, const float* __restrict__ ub2,
                  const float* __restrict__ uW3, const float* __restrict__ ub3,
                  const float* __restrict__ pW1, const float* __restrict__ pb1,
                  const float* __restrict__ pW2, const float* __restrict__ pb2,
                  const float* __restrict__ pW3, const float* __restrict__ pb3,
                  float* __restrict__ state_g, float* __restrict__ outg, int n)
{
    __shared__ float act[BM * AS];
    __shared__ float ldeg[BM];

    const int tid = threadIdx.x;
    const long base = (long)blockIdx.x * BM;
    const int nvar2 = 2 * nvar;
    const int wave = tid >> 6;
    const int lane = tid & 63;

    // ---- CSR gather into act[:, 0:K0] (swizzled); deg -> ldeg
    if constexpr (K0 == 64) {
        // 16 waves x 4 nodes sequential; 64 lanes = 64 features
        for (int i = 0; i < 4; i++) {
            int node = wave * 4 + i;
            long g = base + node;
            int d0 = 0, d1 = 0;
            if (g < n) { d0 = rs[g]; d1 = rs[g + 1]; }
            float acc = 0.0f;
            int e = d0;
            for (; e + 4 <= d1; e += 4) {
                int s0 = col[e], s1 = col[e + 1], s2 = col[e + 2], s3 = col[e + 3];
                float a0 = (s0 < nvar2) ? srcdat[(long)s0 * 64 + lane] : 0.0f;
                float a1 = (s1 < nvar2) ? srcdat[(long)s1 * 64 + lane] : 0.0f;
                float a2 = (s2 < nvar2) ? srcdat[(long)s2 * 64 + lane] : 0.0f;
                float a3 = (s3 < nvar2) ? srcdat[(long)s3 * 64 + lane] : 0.0f;
                acc += a0 + a1 + a2 + a3;
            }
            for (; e < d1; e++) {
                int s = col[e];
                if (s < nvar2) acc += srcdat[(long)s * 64 + lane];
            }
            act[swz(node, lane)] = acc;
            if (lane == 0) ldeg[node] = (float)(d1 - d0);
        }
    } else {
        // 16 lanes = features, 4 nodes per wave concurrently, 1 pass
        const int f = lane & 15, sub = lane >> 4;
        {
            int node = wave * 4 + sub;
            long g = base + node;
            int d0 = 0, d1 = 0;
            if (g < n) { d0 = rs[g]; d1 = rs[g + 1]; }
            float acc = 0.0f;
            int e = d0;
            for (; e + 2 <= d1; e += 2) {
                int s0 = col[e], s1 = col[e + 1];
                float a0 = 0.0f, a1 = 0.0f;
                if (s0 < nvar2) {
                    a0 = srcdat[(long)((s0 < nvar) ? s0 : s0 - nvar) * 16 + f];
                    if (s0 >= nvar) a0 = -a0;
                }
                if (s1 < nvar2) {
                    a1 = srcdat[(long)((s1 < nvar) ? s1 : s1 - nvar) * 16 + f];
                    if (s1 >= nvar) a1 = -a1;
                }
                acc += a0 + a1;
            }
            for (; e < d1; e++) {
                int s = col[e];
                if (s < nvar2) {
                    float a = srcdat[(long)((s < nvar) ? s : s - nvar) * 16 + f];
                    acc += (s < nvar) ? a : -a;
                }
            }
            act[swz(node, f)] = acc;
            if (f == 0) ldeg[node] = (float)(d1 - d0);
        }
    }
    // ---- stage x into cols 64..66, zero col 67
    for (int idx = tid; idx < BM * 4; idx += TPB) {
        int node = idx >> 2, j = idx & 3;
        float v = 0.0f;
        if (j < 3 && base + node < n) v = xg[(base + node) * 3 + j];
        act[swz(node, 64 + j)] = v;
    }
    __syncthreads();

    // ---- layer0: msg = gather@W0 + deg*b0 (reads 0:K0, writes 0:64)
    scalar_gemm<64, false>(act, W0, b0, ldeg, K0, K0, nullptr, base, n);
    // ---- update MLP (uW1 is 67x128; K_pad=68 with wrow clamp, act[67]=0)
    scalar_gemm<128, true >(act, uW1, ub1, nullptr, 67, 68, nullptr, base, n);
    scalar_gemm<128, true >(act, uW2, ub2, nullptr, 128, 128, nullptr, base, n);
    scalar_gemm<64, false>(act, uW3, ub3, nullptr, 128, 128, state_g, base, n);
    // ---- predictor MLP
    scalar_gemm<128, true >(act, pW1, pb1, nullptr, 64, 64, nullptr, base, n);
    scalar_gemm<128, true >(act, pW2, pb2, nullptr, 128, 128, nullptr, base, n);

    // ---- predictor layer3: 128 -> 2 (tiny; pW3 hot in cache)
    if (tid < 128) {
        int r = tid >> 1, c = tid & 1;
        float acc = pb3[c];
        for (int k = 0; k < 128; k += 4) {
            float4 a = *(const float4*)(act + r * AS + (((k >> 2) ^ (r & 7)) << 2));
            acc = fmaf(a.x, pW3[(k + 0) * 2 + c], acc);
            acc = fmaf(a.y, pW3[(k + 1) * 2 + c], acc);
            acc = fmaf(a.z, pW3[(k + 2) * 2 + c], acc);
            acc = fmaf(a.w, pW3[(k + 3) * 2 + c], acc);
        }
        if (base + r < n) outg[(base + r) * 2 + c] = acc;
    }
}

// ===========================================================================
extern "C" void kernel_launch(void* const* d_in, const int* in_sizes, int n_in,
                              void* d_out, int out_size, void* d_ws, size_t ws_size,
                              hipStream_t stream)
{
    const float* x    = (const float*)d_in[0];
    const int*   ei   = (const int*)d_in[1];
    // d_in[2] = gate_type: fixed ordering [VAR*nvar, NEGVAR*nvar, CLAUSE*ncla]
    const float* posr = (const float*)d_in[3];
    const float* Wr   = (const float*)d_in[4];
    const float* br   = (const float*)d_in[5];
    const float* Wc   = (const float*)d_in[6];
    const float* bc   = (const float*)d_in[7];
    const float* uW1  = (const float*)d_in[8];
    const float* ub1  = (const float*)d_in[9];
    const float* uW2  = (const float*)d_in[10];
    const float* ub2  = (const float*)d_in[11];
    const float* uW3  = (const float*)d_in[12];
    const float* ub3  = (const float*)d_in[13];
    const float* pW1  = (const float*)d_in[14];
    const float* pb1  = (const float*)d_in[15];
    const float* pW2  = (const float*)d_in[16];
    const float* pb2  = (const float*)d_in[17];
    const float* pW3  = (const float*)d_in[18];
    const float* pb3  = (const float*)d_in[19];

    const int N     = in_sizes[0] / 3;
    const int E     = in_sizes[1] / 2;
    const int nvar  = in_sizes[3] / 16;
    const int nvar2 = 2 * nvar;
    const int ncla  = N - nvar2;

    // workspace carve-out
    int* cnt    = (int*)d_ws;              // [N]
    int* rs     = cnt + N;                 // [N+1]
    int* cursor = rs + N + 1;              // [N]
    int* part   = cursor + N;              // [2048]
    int* col    = part + 2048;             // [E]
    size_t foff = ((size_t)(col + E - (int*)d_ws) + 3) & ~(size_t)3;
    float* state = (float*)d_ws + foff;    // [2nvar*64]

    hipMemsetAsync(cnt, 0, (size_t)N * sizeof(int), stream);

    const int nb = (N + 2047) / 2048;
    count_kernel<<<(E + 255) / 256, 256, 0, stream>>>(ei, cnt, E);
    scan_blocks<<<nb, 256, 0, stream>>>(cnt, rs, part, N);
    scan_part<<<1, 256, 0, stream>>>(part, nb);
    scan_fixup<<<(N + 255) / 256, 256, 0, stream>>>(rs, cursor, part, N, E);
    scatter_kernel<<<(E + 255) / 256, 256, 0, stream>>>(ei, cursor, col, E);

    {   // var + negvar partitions (gather pos_random via CSR)
        int blocks = (nvar2 + BM - 1) / BM;
        fused_kernel<16><<<blocks, TPB, 0, stream>>>(
            rs, col, posr, nvar, x, Wr, br,
            uW1, ub1, uW2, ub2, uW3, ub3,
            pW1, pb1, pW2, pb2, pW3, pb3,
            state, (float*)d_out, nvar2);
    }

    {   // clause partition (gather state via CSR, rows offset by 2nvar)
        int blocks = (ncla + BM - 1) / BM;
        fused_kernel<64><<<blocks, TPB, 0, stream>>>(
            rs + nvar2, col, state, nvar, x + (size_t)nvar2 * 3, Wc, bc,
            uW1, ub1, uW2, ub2, uW3, ub3,
            pW1, pb1, pW2, pb2, pW3, pb3,
            nullptr, (float*)d_out + (size_t)nvar2 * 2, ncla);
    }
}

// Round 12
// 1433.351 us; speedup vs baseline: 1.0990x; 1.0990x over previous
//
#include <hip/hip_runtime.h>

#define TPB 512
#define BM 64
#define AS 128   // activation row stride in floats (swizzled)

// ===========================================================================
// CSR build: count -> block scan -> fixup -> scatter. Rebuilt every call.
// ===========================================================================
__global__ void count_kernel(const int* __restrict__ ei, int* __restrict__ cnt, int E)
{
    int e = blockIdx.x * blockDim.x + threadIdx.x;
    if (e >= E) return;
    atomicAdd(cnt + ei[E + e], 1);
}

__global__ void scan_blocks(const int* __restrict__ cnt, int* __restrict__ rs,
                            int* __restrict__ part, int N)
{
    __shared__ int sums[256];
    int t = threadIdx.x;
    int base = blockIdx.x * 2048 + t * 8;
    int v[8], s = 0;
#pragma unroll
    for (int i = 0; i < 8; i++) { int idx = base + i; v[i] = (idx < N) ? cnt[idx] : 0; s += v[i]; }
    sums[t] = s;
    __syncthreads();
    for (int off = 1; off < 256; off <<= 1) {
        int x = (t >= off) ? sums[t - off] : 0;
        __syncthreads();
        if (t >= off) sums[t] += x;
        __syncthreads();
    }
    int run = (t == 0) ? 0 : sums[t - 1];
#pragma unroll
    for (int i = 0; i < 8; i++) { int idx = base + i; if (idx < N) rs[idx] = run; run += v[i]; }
    if (t == 255) part[blockIdx.x] = sums[255];
}

__global__ void scan_part(int* __restrict__ part, int nb)
{
    __shared__ int sums[256];
    int t = threadIdx.x;
    int base = t * 8;
    int v[8], s = 0;
#pragma unroll
    for (int i = 0; i < 8; i++) { int idx = base + i; v[i] = (idx < nb) ? part[idx] : 0; s += v[i]; }
    sums[t] = s;
    __syncthreads();
    for (int off = 1; off < 256; off <<= 1) {
        int x = (t >= off) ? sums[t - off] : 0;
        __syncthreads();
        if (t >= off) sums[t] += x;
        __syncthreads();
    }
    int run = (t == 0) ? 0 : sums[t - 1];
#pragma unroll
    for (int i = 0; i < 8; i++) { int idx = base + i; if (idx < nb) part[idx] = run; run += v[i]; }
}

__global__ void scan_fixup(int* __restrict__ rs, int* __restrict__ cursor,
                           const int* __restrict__ part, int N, int E)
{
    int i = blockIdx.x * blockDim.x + threadIdx.x;
    if (i < N) { int v = rs[i] + part[i >> 11]; rs[i] = v; cursor[i] = v; }
    if (i == 0) rs[N] = E;
}

__global__ void scatter_kernel(const int* __restrict__ ei, int* __restrict__ cursor,
                               int* __restrict__ col, int E)
{
    int e = blockIdx.x * blockDim.x + threadIdx.x;
    if (e >= E) return;
    int d = ei[E + e];
    int p = atomicAdd(cursor + d, 1);
    col[p] = ei[e];
}

// ===========================================================================
// Standalone CSR gathers (separate kernels so their register pressure does
// NOT inflate the MLP kernel's budget — r9/r11 showed fused gather spills
// at the 32-reg granule). No launch bounds: latency-bound, regs are free.
// ===========================================================================
// clause gather: agg_c[node][0:64] = sum over in-edges of state[src], src<nvar2
__global__ void gather_cla_kernel(const int* __restrict__ rs, const int* __restrict__ col,
                                  const float* __restrict__ state,
                                  float* __restrict__ agg, float* __restrict__ deg,
                                  int nvar2, int n)
{
    int gwave = (blockIdx.x * blockDim.x + threadIdx.x) >> 6;
    int lane = threadIdx.x & 63;
    for (int i = 0; i < 8; i++) {
        int node = gwave * 8 + i;
        if (node >= n) return;                 // node wave-uniform
        int d0 = rs[node], d1 = rs[node + 1];
        float acc = 0.0f;
        int e = d0;
        for (; e + 4 <= d1; e += 4) {
            int s0 = col[e], s1 = col[e + 1], s2 = col[e + 2], s3 = col[e + 3];
            float a0 = (s0 < nvar2) ? state[(long)s0 * 64 + lane] : 0.0f;
            float a1 = (s1 < nvar2) ? state[(long)s1 * 64 + lane] : 0.0f;
            float a2 = (s2 < nvar2) ? state[(long)s2 * 64 + lane] : 0.0f;
            float a3 = (s3 < nvar2) ? state[(long)s3 * 64 + lane] : 0.0f;
            acc += a0 + a1 + a2 + a3;
        }
        for (; e < d1; e++) {
            int s = col[e];
            if (s < nvar2) acc += state[(long)s * 64 + lane];
        }
        agg[(long)node * 64 + lane] = acc;
        if (lane == 0) deg[node] = (float)(d1 - d0);
    }
}

// var/negvar gather: agg_v[node][0:16] = sum of +/-pos_random[src%nvar]
__global__ void gather_var_kernel(const int* __restrict__ rs, const int* __restrict__ col,
                                  const float* __restrict__ posr,
                                  float* __restrict__ agg, float* __restrict__ deg,
                                  int nvar, int n2)
{
    int gwave = (blockIdx.x * blockDim.x + threadIdx.x) >> 6;
    int lane = threadIdx.x & 63;
    int f = lane & 15, sub = lane >> 4;
    int nvar2 = 2 * nvar;
    for (int i = 0; i < 2; i++) {
        int node = gwave * 8 + i * 4 + sub;
        if (node < n2) {
            int d0 = rs[node], d1 = rs[node + 1];
            float acc = 0.0f;
            int e = d0;
            for (; e + 2 <= d1; e += 2) {
                int s0 = col[e], s1 = col[e + 1];
                float a0 = 0.0f, a1 = 0.0f;
                if (s0 < nvar2) {
                    a0 = posr[(long)((s0 < nvar) ? s0 : s0 - nvar) * 16 + f];
                    if (s0 >= nvar) a0 = -a0;
                }
                if (s1 < nvar2) {
                    a1 = posr[(long)((s1 < nvar) ? s1 : s1 - nvar) * 16 + f];
                    if (s1 >= nvar) a1 = -a1;
                }
                acc += a0 + a1;
            }
            for (; e < d1; e++) {
                int s = col[e];
                if (s < nvar2) {
                    float a = posr[(long)((s < nvar) ? s : s - nvar) * 16 + f];
                    acc += (s < nvar) ? a : -a;
                }
            }
            agg[(long)node * 16 + f] = acc;
            if (f == 0) deg[node] = (float)(d1 - d0);
        }
    }
}

// ===========================================================================
// act LDS swizzle: float4-slot XOR'd with (row&7); row-stride (lane=row)
// accesses spread across all banks.
// ===========================================================================
__device__ __forceinline__ int swz(int r, int col)
{
    return r * AS + ((((col >> 2) ^ (r & 7)) << 2) | (col & 3));
}

// ===========================================================================
// Scalar-weight GEMM layer: wave = 64 rows (lane=row) x CW=C/8 columns.
// W[k][c] wave-uniform -> s_load through K$ (SGPR operand of v_fma_f32,
// zero VGPR cost); 1 ds_read_b128 of act per 4 k per lane.
//   act[r][0:C] = f(sum_k act[r][k]*W[k][c] + scale(r)*bias[c])  in place
// ===========================================================================
template<int C, bool RELU>
__device__ __forceinline__ void scalar_gemm(
    float* __restrict__ act,
    const float* __restrict__ Wg, const float* __restrict__ bias_g,
    const float* __restrict__ ldeg,            // non-null: scale = ldeg[r]
    int K_real, int K_pad,                     // K_pad multiple of 4
    float* __restrict__ state_g, long base, int n)
{
    constexpr int CW = C / 8;                  // columns per wave (16 or 8)
    const int tid  = threadIdx.x;
    const int wid  = __builtin_amdgcn_readfirstlane(tid >> 6);  // uniform
    const int lane = tid & 63;
    const int r    = lane;                     // lane = row
    const int c0   = wid * CW;                 // wave-uniform column base

    float acc[CW];
#pragma unroll
    for (int j = 0; j < CW; j++) acc[j] = 0.0f;

    for (int k4 = 0; k4 < K_pad; k4 += 4) {
        float4 a = *(const float4*)(act + r * AS + (((k4 >> 2) ^ (r & 7)) << 2));
#pragma unroll
        for (int kk = 0; kk < 4; kk++) {
            int gk = k4 + kk;
            int wrow = (gk < K_real) ? gk : 0;       // clamp (act pad col = 0)
            float av = (&a.x)[kk];
            const float* wr = Wg + (long)wrow * C + c0;   // uniform -> s_load
#pragma unroll
            for (int j4 = 0; j4 < CW / 4; j4++) {
                float4 wv = *(const float4*)(wr + j4 * 4);
                acc[j4 * 4 + 0] = fmaf(av, wv.x, acc[j4 * 4 + 0]);
                acc[j4 * 4 + 1] = fmaf(av, wv.y, acc[j4 * 4 + 1]);
                acc[j4 * 4 + 2] = fmaf(av, wv.z, acc[j4 * 4 + 2]);
                acc[j4 * 4 + 3] = fmaf(av, wv.w, acc[j4 * 4 + 3]);
            }
        }
    }
    float scale = (ldeg != nullptr) ? ldeg[r] : 1.0f;
    __syncthreads();       // all waves' act reads complete
#pragma unroll
    for (int j4 = 0; j4 < CW / 4; j4++) {
        int cc = c0 + j4 * 4;
        float4 bv = *(const float4*)(bias_g + cc);        // uniform -> s_load
        float4 o;
        o.x = acc[j4 * 4 + 0] + scale * bv.x;
        o.y = acc[j4 * 4 + 1] + scale * bv.y;
        o.z = acc[j4 * 4 + 2] + scale * bv.z;
        o.w = acc[j4 * 4 + 3] + scale * bv.w;
        if (RELU) {
            o.x = fmaxf(o.x, 0.0f); o.y = fmaxf(o.y, 0.0f);
            o.z = fmaxf(o.z, 0.0f); o.w = fmaxf(o.w, 0.0f);
        }
        *(float4*)(act + r * AS + (((cc >> 2) ^ (r & 7)) << 2)) = o;
        if (state_g != nullptr && base + r < n)
            *(float4*)(state_g + (base + r) * 64 + cc) = o;
    }
    __syncthreads();       // new act visible
}

// ===========================================================================
// Pure-GEMM MLP kernel (gather removed): stage agg -> LDS, layer0 -> update
// MLP -> predictor. Peak regs = gemm only (~28) -> fits the 32-reg granule
// (launch_bounds(512,8) -> cap 32) WITHOUT spill -> 8 waves/SIMD with 32KB
// LDS (4 blocks/CU).
// ===========================================================================
template<int K0>
__global__ __launch_bounds__(TPB, 8)
void mlp_kernel(const float* __restrict__ agg, const float* __restrict__ deg,
                const float* __restrict__ xg,
                const float* __restrict__ W0, const float* __restrict__ b0,
                const float* __restrict__ uW1, const float* __restrict__ ub1,
                const float* __restrict__ uW2, const float* __restrict__ ub2,
                const float* __restrict__ uW3, const float* __restrict__ ub3,
                const float* __restrict__ pW1, const float* __restrict__ pb1,
                const float* __restrict__ pW2, const float* __restrict__ pb2,
                const float* __restrict__ pW3, const float* __restrict__ pb3,
                float* __restrict__ state_g, float* __restrict__ outg, int n)
{
    __shared__ float act[BM * AS];
    __shared__ float ldeg[BM];

    const int tid = threadIdx.x;
    const long base = (long)blockIdx.x * BM;
    constexpr int KSH = (K0 == 64) ? 6 : 4;

    // ---- stage agg -> act[:, 0:K0] (coalesced read, swizzled write)
    for (int idx = tid; idx < BM * K0; idx += TPB) {
        int node = idx >> KSH, j = idx & (K0 - 1);
        float v = (base + node < n) ? agg[base * K0 + idx] : 0.0f;
        act[swz(node, j)] = v;
    }
    if (tid < BM) ldeg[tid] = (base + tid < n) ? deg[base + tid] : 0.0f;
    // ---- stage x into cols 64..66, zero col 67
    for (int idx = tid; idx < BM * 4; idx += TPB) {
        int node = idx >> 2, j = idx & 3;
        float v = 0.0f;
        if (j < 3 && base + node < n) v = xg[(base + node) * 3 + j];
        act[swz(node, 64 + j)] = v;
    }
    __syncthreads();

    // ---- layer0: msg = agg@W0 + deg*b0 (reads 0:K0, writes 0:64)
    scalar_gemm<64, false>(act, W0, b0, ldeg, K0, K0, nullptr, base, n);
    // ---- update MLP (uW1 is 67x128; K_pad=68 with wrow clamp, act[67]=0)
    scalar_gemm<128, true >(act, uW1, ub1, nullptr, 67, 68, nullptr, base, n);
    scalar_gemm<128, true >(act, uW2, ub2, nullptr, 128, 128, nullptr, base, n);
    scalar_gemm<64, false>(act, uW3, ub3, nullptr, 128, 128, state_g, base, n);
    // ---- predictor MLP
    scalar_gemm<128, true >(act, pW1, pb1, nullptr, 64, 64, nullptr, base, n);
    scalar_gemm<128, true >(act, pW2, pb2, nullptr, 128, 128, nullptr, base, n);

    // ---- predictor layer3: 128 -> 2 (tiny; pW3 hot in cache)
    if (tid < 128) {
        int r = tid >> 1, c = tid & 1;
        float acc = pb3[c];
        for (int k = 0; k < 128; k += 4) {
            float4 a = *(const float4*)(act + r * AS + (((k >> 2) ^ (r & 7)) << 2));
            acc = fmaf(a.x, pW3[(k + 0) * 2 + c], acc);
            acc = fmaf(a.y, pW3[(k + 1) * 2 + c], acc);
            acc = fmaf(a.z, pW3[(k + 2) * 2 + c], acc);
            acc = fmaf(a.w, pW3[(k + 3) * 2 + c], acc);
        }
        if (base + r < n) outg[(base + r) * 2 + c] = acc;
    }
}

// ===========================================================================
extern "C" void kernel_launch(void* const* d_in, const int* in_sizes, int n_in,
                              void* d_out, int out_size, void* d_ws, size_t ws_size,
                              hipStream_t stream)
{
    const float* x    = (const float*)d_in[0];
    const int*   ei   = (const int*)d_in[1];
    // d_in[2] = gate_type: fixed ordering [VAR*nvar, NEGVAR*nvar, CLAUSE*ncla]
    const float* posr = (const float*)d_in[3];
    const float* Wr   = (const float*)d_in[4];
    const float* br   = (const float*)d_in[5];
    const float* Wc   = (const float*)d_in[6];
    const float* bc   = (const float*)d_in[7];
    const float* uW1  = (const float*)d_in[8];
    const float* ub1  = (const float*)d_in[9];
    const float* uW2  = (const float*)d_in[10];
    const float* ub2  = (const float*)d_in[11];
    const float* uW3  = (const float*)d_in[12];
    const float* ub3  = (const float*)d_in[13];
    const float* pW1  = (const float*)d_in[14];
    const float* pb1  = (const float*)d_in[15];
    const float* pW2  = (const float*)d_in[16];
    const float* pb2  = (const float*)d_in[17];
    const float* pW3  = (const float*)d_in[18];
    const float* pb3  = (const float*)d_in[19];

    const int N     = in_sizes[0] / 3;
    const int E     = in_sizes[1] / 2;
    const int nvar  = in_sizes[3] / 16;
    const int nvar2 = 2 * nvar;
    const int ncla  = N - nvar2;

    // workspace carve-out
    int* cnt    = (int*)d_ws;              // [N]
    int* rs     = cnt + N;                 // [N+1]
    int* cursor = rs + N + 1;              // [N]
    int* part   = cursor + N;              // [2048]
    int* col    = part + 2048;             // [E]
    size_t foff = ((size_t)(col + E - (int*)d_ws) + 3) & ~(size_t)3;
    float* state = (float*)d_ws + foff;    // [2nvar*64]
    float* agg_v = state + (size_t)nvar2 * 64;   // [2nvar*16]
    float* deg_v = agg_v + (size_t)nvar2 * 16;   // [2nvar]
    float* agg_c = deg_v + nvar2;                // [ncla*64]
    float* deg_c = agg_c + (size_t)ncla * 64;    // [ncla]

    hipMemsetAsync(cnt, 0, (size_t)N * sizeof(int), stream);

    const int nb = (N + 2047) / 2048;
    count_kernel<<<(E + 255) / 256, 256, 0, stream>>>(ei, cnt, E);
    scan_blocks<<<nb, 256, 0, stream>>>(cnt, rs, part, N);
    scan_part<<<1, 256, 0, stream>>>(part, nb);
    scan_fixup<<<(N + 255) / 256, 256, 0, stream>>>(rs, cursor, part, N, E);
    scatter_kernel<<<(E + 255) / 256, 256, 0, stream>>>(ei, cursor, col, E);

    {   // var/negvar gather (CSR -> agg_v, deg_v)
        int blocks = (nvar2 + 31) / 32;    // 4 waves x 8 nodes per block
        gather_var_kernel<<<blocks, 256, 0, stream>>>(rs, col, posr,
                                                      agg_v, deg_v, nvar, nvar2);
    }
    {   // var/negvar MLP (writes state + out)
        int blocks = (nvar2 + BM - 1) / BM;
        mlp_kernel<16><<<blocks, TPB, 0, stream>>>(
            agg_v, deg_v, x, Wr, br,
            uW1, ub1, uW2, ub2, uW3, ub3,
            pW1, pb1, pW2, pb2, pW3, pb3,
            state, (float*)d_out, nvar2);
    }
    {   // clause gather (CSR rows offset by 2nvar -> agg_c, deg_c)
        int blocks = (ncla + 31) / 32;
        gather_cla_kernel<<<blocks, 256, 0, stream>>>(rs + nvar2, col, state,
                                                      agg_c, deg_c, nvar2, ncla);
    }
    {   // clause MLP
        int blocks = (ncla + BM - 1) / BM;
        mlp_kernel<64><<<blocks, TPB, 0, stream>>>(
            agg_c, deg_c, x + (size_t)nvar2 * 3, Wc, bc,
            uW1, ub1, uW2, ub2, uW3, ub3,
            pW1, pb1, pW2, pb2, pW3, pb3,
            nullptr, (float*)d_out + (size_t)nvar2 * 2, ncla);
    }
}